// Round 5
// baseline (399.738 us; speedup 1.0000x reference)
//
#include <hip/hip_runtime.h>
#include <hip/hip_bf16.h>
#include <stdint.h>

#define B_SZ   4096
#define TWO_B  8192
#define D_DIM  2048
#define N_TOT  15000000
#define RHO    0.8f
#define NT     64         // 2048 / 32 K-tiles
#define NJOB   1056       // sum over C of min(2C+2,64) jobs of 128x256
#define GRAM_THREADS 512

typedef __attribute__((ext_vector_type(8))) __bf16 bf16x8;
typedef __attribute__((ext_vector_type(4))) float f32x4;
typedef unsigned short ushort_t;

// ---------- helpers ----------
__device__ __forceinline__ ushort_t f2bf(float v) {
    __hip_bfloat16 h = __float2bfloat16(v);
    return *reinterpret_cast<ushort_t*>(&h);
}
__device__ __forceinline__ float waveReduceSum(float v) {
#pragma unroll
    for (int off = 32; off >= 1; off >>= 1) v += __shfl_down(v, off, 64);
    return v;
}
__device__ __forceinline__ void gload_lds16(const void* g, void* l) {
    __builtin_amdgcn_global_load_lds(
        (const __attribute__((address_space(1))) void*)(uintptr_t)g,
        (__attribute__((address_space(3))) void*)(uintptr_t)l,
        16, 0, 0);
}

// ---------- kernel 1: paired normalize -> bf16, + positive-pair dot ----------
// Block i handles rows i and i+B: normalizes both, pos[i] = dot(f32) * inv_i * inv_j.
__global__ __launch_bounds__(256) void knorm2(const float* __restrict__ feat,
                                              ushort_t* __restrict__ fbf,
                                              float* __restrict__ posdot) {
    int i = blockIdx.x;           // [0, B)
    int tid = threadIdx.x;
    const float4* ra = reinterpret_cast<const float4*>(feat + (size_t)i * D_DIM);
    const float4* rb = reinterpret_cast<const float4*>(feat + (size_t)(i + B_SZ) * D_DIM);
    float4 a0 = ra[tid * 2], a1 = ra[tid * 2 + 1];
    float4 b0 = rb[tid * 2], b1 = rb[tid * 2 + 1];
    float sa = a0.x*a0.x + a0.y*a0.y + a0.z*a0.z + a0.w*a0.w
             + a1.x*a1.x + a1.y*a1.y + a1.z*a1.z + a1.w*a1.w;
    float sb = b0.x*b0.x + b0.y*b0.y + b0.z*b0.z + b0.w*b0.w
             + b1.x*b1.x + b1.y*b1.y + b1.z*b1.z + b1.w*b1.w;
    float dp = a0.x*b0.x + a0.y*b0.y + a0.z*b0.z + a0.w*b0.w
             + a1.x*b1.x + a1.y*b1.y + a1.z*b1.z + a1.w*b1.w;
    sa = waveReduceSum(sa);
    sb = waveReduceSum(sb);
    dp = waveReduceSum(dp);
    __shared__ float wsum[3][4];
    if ((tid & 63) == 0) {
        int wv = tid >> 6;
        wsum[0][wv] = sa; wsum[1][wv] = sb; wsum[2][wv] = dp;
    }
    __syncthreads();
    float ta = wsum[0][0] + wsum[0][1] + wsum[0][2] + wsum[0][3];
    float tb = wsum[1][0] + wsum[1][1] + wsum[1][2] + wsum[1][3];
    float td = wsum[2][0] + wsum[2][1] + wsum[2][2] + wsum[2][3];
    float ia = 1.0f / fmaxf(sqrtf(ta), 1e-12f);
    float ib = 1.0f / fmaxf(sqrtf(tb), 1e-12f);
    if (tid == 0) posdot[i] = td * ia * ib;
    uint4 oa, ob;
    oa.x = (unsigned)f2bf(a0.x * ia) | ((unsigned)f2bf(a0.y * ia) << 16);
    oa.y = (unsigned)f2bf(a0.z * ia) | ((unsigned)f2bf(a0.w * ia) << 16);
    oa.z = (unsigned)f2bf(a1.x * ia) | ((unsigned)f2bf(a1.y * ia) << 16);
    oa.w = (unsigned)f2bf(a1.z * ia) | ((unsigned)f2bf(a1.w * ia) << 16);
    ob.x = (unsigned)f2bf(b0.x * ib) | ((unsigned)f2bf(b0.y * ib) << 16);
    ob.y = (unsigned)f2bf(b0.z * ib) | ((unsigned)f2bf(b0.w * ib) << 16);
    ob.z = (unsigned)f2bf(b1.x * ib) | ((unsigned)f2bf(b1.y * ib) << 16);
    ob.w = (unsigned)f2bf(b1.z * ib) | ((unsigned)f2bf(b1.w * ib) << 16);
    reinterpret_cast<uint4*>(fbf + (size_t)i * D_DIM)[tid] = oa;
    reinterpret_cast<uint4*>(fbf + (size_t)(i + B_SZ) * D_DIM)[tid] = ob;
}

// ---------- kernel 2: symmetric Gram, 128x256 jobs, BK=32, QUAD-buffer (depth-3),
//            counted vmcnt(6), fused masked-exp reductions + fused s/u/tau copy.
// Job (R,C): rows 128R.., cols 256C.., exists iff C >= R>>1 (C-major enumeration).
__global__ __launch_bounds__(GRAM_THREADS, 2) void kgram(
        const ushort_t* __restrict__ fbf,
        const float* __restrict__ tau_buf, const int* __restrict__ index,
        float* __restrict__ E, float* __restrict__ F,
        const float4* __restrict__ sIn, const float4* __restrict__ uIn,
        const float4* __restrict__ tIn, float* __restrict__ out) {
    const int raw = (int)blockIdx.x;
    const int bid = (raw & 7) * (NJOB / 8) + (raw >> 3);   // chunked XCD swizzle (1056 = 8*132)
    // decode job (C-major): largest C with C*C+C <= bid; R = bid - C*C - C
    int C = (int)((sqrtf((float)(4 * bid + 1)) - 1.0f) * 0.5f);
    while (C * C + C > bid) --C;
    while ((C + 1) * (C + 1) + (C + 1) <= bid) ++C;
    const int R = bid - C * C - C;
    const int r0 = R * 128, c0 = C * 256;

    const int tid = threadIdx.x;
    const int lane = tid & 63;
    const int w = tid >> 6;            // wave 0..7
    const int wr = w >> 2;             // 0..1 (M)
    const int wc = w & 3;              // 0..3 (N)
    const int l15 = lane & 15, lhi = lane >> 4;

    __shared__ alignas(16) ushort_t As[4][128 * 32];   // 32 KB
    __shared__ alignas(16) ushort_t Bs[4][256 * 32];   // 64 KB

    f32x4 acc[4][4] = {};

    // staging: one wave-gload fills 16 rows x 32 cols (64 lanes x 16B), linear LDS.
    // swizzle via source: global chunk = (l&3) ^ ((l>>3)&3)
    const int srow = lane >> 2;
    const int schk = (lane & 3) ^ ((lane >> 3) & 3);
    const uint32_t gA  = (uint32_t)(r0 + w * 16 + srow) * D_DIM + schk * 8;
    const uint32_t gB0 = (uint32_t)(c0 + w * 32 + srow) * D_DIM + schk * 8;
    const uint32_t gB1 = gB0 + 16u * D_DIM;
    const int lA  = w * 16 * 32;
    const int lB0 = w * 32 * 32;
    const int lB1 = (w * 32 + 16) * 32;

#define STAGE(buf, t)                                                    \
    do {                                                                 \
        uint32_t k_ = (uint32_t)(t) * 32u;                               \
        gload_lds16(fbf + gA + k_,  &As[buf][lA]);                       \
        gload_lds16(fbf + gB0 + k_, &Bs[buf][lB0]);                      \
        gload_lds16(fbf + gB1 + k_, &Bs[buf][lB1]);                      \
    } while (0)

    // prologue: stage tiles 0..2; ensure tile 0 landed (tiles 1,2 stay in flight)
    STAGE(0, 0);
    STAGE(1, 1);
    STAGE(2, 2);
    asm volatile("s_waitcnt vmcnt(6)" ::: "memory");
    __builtin_amdgcn_sched_barrier(0);
    __builtin_amdgcn_s_barrier();

    const int rdch = (lhi ^ ((l15 >> 1) & 3)) * 8;   // swizzled read chunk (elements)
    int bufc = 0;
    for (int t = 0; t < NT; ++t) {
        if (t + 3 < NT) STAGE((bufc + 3) & 3, t + 3);
        const ushort_t* __restrict__ A_l = &As[bufc][0];
        const ushort_t* __restrict__ B_l = &Bs[bufc][0];
        bf16x8 af[4], bfr[4];
#pragma unroll
        for (int m = 0; m < 4; ++m)
            af[m] = *reinterpret_cast<const bf16x8*>(&A_l[(wr * 64 + m * 16 + l15) * 32 + rdch]);
#pragma unroll
        for (int n = 0; n < 4; ++n)
            bfr[n] = *reinterpret_cast<const bf16x8*>(&B_l[(wc * 64 + n * 16 + l15) * 32 + rdch]);
        __builtin_amdgcn_s_setprio(1);
#pragma unroll
        for (int m = 0; m < 4; ++m)
#pragma unroll
            for (int n = 0; n < 4; ++n)
                acc[m][n] = __builtin_amdgcn_mfma_f32_16x16x32_bf16(af[m], bfr[n], acc[m][n], 0, 0, 0);
        __builtin_amdgcn_s_setprio(0);
        if (t < NT - 3) {
            asm volatile("s_waitcnt vmcnt(6)" ::: "memory");   // tile t+1 landed; t+2,t+3 fly
        } else if (t == NT - 3) {
            asm volatile("s_waitcnt vmcnt(3)" ::: "memory");
        } else if (t == NT - 2) {
            asm volatile("s_waitcnt vmcnt(0)" ::: "memory");
        }
        __builtin_amdgcn_sched_barrier(0);
        if (t < NT - 1) __builtin_amdgcn_s_barrier();
        bufc = (bufc + 1) & 3;
    }
#undef STAGE

    // ---- epilogue: per element col>row -> direct (row tau) + transposed (col tau) ----
#pragma unroll
    for (int m = 0; m < 4; ++m) {
#pragma unroll
        for (int r = 0; r < 4; ++r) {
            int row_g = r0 + wr * 64 + m * 16 + lhi * 4 + r;
            float it = 1.0f / tau_buf[index[row_g & (B_SZ - 1)]];
            float e = 0.f, f = 0.f;
#pragma unroll
            for (int n = 0; n < 4; ++n) {
                int col_g = c0 + wc * 64 + n * 16 + l15;
                float v = acc[m][n][r];
                if (col_g > row_g && (((row_g ^ col_g) & (B_SZ - 1)) != 0)) {
                    float ex = __expf(v * it);
                    e += ex;
                    f += ex * v;
                }
            }
#pragma unroll
            for (int off = 1; off < 16; off <<= 1) {
                e += __shfl_xor(e, off, 64);
                f += __shfl_xor(f, off, 64);
            }
            if (l15 == 0) {
                atomicAdd(&E[row_g], e);
                atomicAdd(&F[row_g], f);
            }
        }
    }
#pragma unroll
    for (int n = 0; n < 4; ++n) {
        int colT = c0 + wc * 64 + n * 16 + l15;
        float it = 1.0f / tau_buf[index[colT & (B_SZ - 1)]];
        float e = 0.f, f = 0.f;
#pragma unroll
        for (int m = 0; m < 4; ++m) {
#pragma unroll
            for (int r = 0; r < 4; ++r) {
                int row_g = r0 + wr * 64 + m * 16 + lhi * 4 + r;
                float v = acc[m][n][r];
                if (colT > row_g && (((row_g ^ colT) & (B_SZ - 1)) != 0)) {
                    float ex = __expf(v * it);
                    e += ex;
                    f += ex * v;
                }
            }
        }
        e += __shfl_xor(e, 16, 64);
        f += __shfl_xor(f, 16, 64);
        e += __shfl_xor(e, 32, 64);
        f += __shfl_xor(f, 32, 64);
        if (lhi == 0) {
            atomicAdd(&E[colT], e);
            atomicAdd(&F[colT], f);
        }
    }

    // ---- fused bulk copy s/u/tau -> out (fills scheduling bubbles) ----
    {
        typedef float4 __attribute__((aligned(4))) float4u;
        size_t i = (size_t)raw * GRAM_THREADS + tid;
        const size_t stride = (size_t)NJOB * GRAM_THREADS;
        const size_t n4 = N_TOT / 4;
        for (; i < n4; i += stride) {
            *reinterpret_cast<float4u*>(out + 1 + 4 * i) = sIn[i];
            *reinterpret_cast<float4u*>(out + 1 + (size_t)N_TOT + 4 * i) = uIn[i];
            *reinterpret_cast<float4u*>(out + 1 + 2 * (size_t)N_TOT + 4 * i) = tIn[i];
        }
    }
}

// ---------- kernel 3: finalize per positive pair ----------
__global__ __launch_bounds__(64) void kfin(const float* __restrict__ E,
                                           const float* __restrict__ F,
                                           const float* __restrict__ posdot,
                                           const float* __restrict__ s,
                                           const float* __restrict__ tau_buf,
                                           const float* __restrict__ u_buf,
                                           const int* __restrict__ index,
                                           const int* __restrict__ epoch_p,
                                           float* __restrict__ out) {
    int i = blockIdx.x;     // [0, B)
    int lane = threadIdx.x; // [0, 64)
    int idx = index[i];
    bool dup = false;
    for (int j = i + 1 + lane; j < B_SZ; j += 64)
        if (index[j] == idx) dup = true;
    unsigned long long ball = __ballot(dup);

    if (lane == 0) {
        float e1 = E[i], f1 = F[i];
        float e2 = E[i + B_SZ], f2 = F[i + B_SZ];
        const float num_neg = 2.0f * B_SZ - 2.0f;
        float g1 = e1 / num_neg, g2 = e2 / num_neg;
        float s_old = s[idx];
        float tau_i = tau_buf[idx];
        float u_old = u_buf[idx];
        int ep = *epoch_p;
        float s1, s2;
        if (ep == 0) { s1 = g1; s2 = g2; }
        else { s1 = 0.2f * s_old + 0.8f * g1; s2 = 0.2f * s_old + 0.8f * g2; }
        float pos = posdot[i];
        float l1 = f1 / (s1 * num_neg) - pos;
        float l2 = f2 / (s2 * num_neg) - pos;
        atomicAdd(out, (l1 + l2) * (1.0f / B_SZ));
        float gt1 = logf(s1) + RHO - f1 / (tau_i * s1 * num_neg);
        float gt2 = logf(s2) + RHO - f2 / (tau_i * s2 * num_neg);
        float gt = 0.5f * (gt1 + gt2);
        gt = fminf(fmaxf(gt, -3.0f), 3.0f);
        float u_new = 0.1f * u_old + 0.9f * gt;
        float tau_new = fminf(fmaxf(tau_i - 0.001f * u_new, 0.05f), 1.0f);
        if (ball == 0ULL) {  // winner (numpy last-wins)
            out[1 + (size_t)idx] = 0.5f * (s1 + s2);
            out[1 + (size_t)N_TOT + idx] = u_new;
            out[1 + 2 * (size_t)N_TOT + idx] = tau_new;
        }
    }
}

extern "C" void kernel_launch(void* const* d_in, const int* in_sizes, int n_in,
                              void* d_out, int out_size, void* d_ws, size_t ws_size,
                              hipStream_t stream) {
    const float* features = (const float*)d_in[0];
    const float* s        = (const float*)d_in[1];
    const float* tau_buf  = (const float*)d_in[2];
    const float* u_buf    = (const float*)d_in[3];
    const int*   index    = (const int*)d_in[4];
    const int*   epoch    = (const int*)d_in[5];
    float* out = (float*)d_out;
    char* ws = (char*)d_ws;

    // workspace layout
    ushort_t* fbf    = (ushort_t*)(ws);                  // 33,554,432 B
    float*    E      = (float*)(ws + 33554432);          // 32 KB
    float*    F      = (float*)(ws + 33587200);          // 32 KB
    float*    posdot = (float*)(ws + 33619968);          // 16 KB

    hipMemsetAsync(d_out, 0, sizeof(float), stream);           // loss accumulator
    hipMemsetAsync(E, 0, 2 * TWO_B * sizeof(float), stream);   // E and F (contiguous)

    knorm2<<<B_SZ, 256, 0, stream>>>(features, fbf, posdot);
    kgram<<<NJOB, GRAM_THREADS, 0, stream>>>(fbf, tau_buf, index, E, F,
                                             (const float4*)s, (const float4*)u_buf,
                                             (const float4*)tau_buf, out);
    kfin<<<B_SZ, 64, 0, stream>>>(E, F, posdot, s, tau_buf, u_buf, index, epoch, out);
}

// Round 6
// 366.145 us; speedup vs baseline: 1.0917x; 1.0917x over previous
//
#include <hip/hip_runtime.h>
#include <hip/hip_bf16.h>
#include <stdint.h>

#define B_SZ   4096
#define TWO_B  8192
#define D_DIM  2048
#define N_TOT  15000000
#define RHO    0.8f
#define NT     64         // 2048 / 32 K-tiles
#define NJOB   528        // 496 off-diag (R<C) + 32 diag (R==C), 256x256 each
#define GRAM_THREADS 1024

typedef __attribute__((ext_vector_type(8))) __bf16 bf16x8;
typedef __attribute__((ext_vector_type(4))) float f32x4;
typedef unsigned short ushort_t;

// ---------- helpers ----------
__device__ __forceinline__ ushort_t f2bf(float v) {
    __hip_bfloat16 h = __float2bfloat16(v);
    return *reinterpret_cast<ushort_t*>(&h);
}
__device__ __forceinline__ float waveReduceSum(float v) {
#pragma unroll
    for (int off = 32; off >= 1; off >>= 1) v += __shfl_down(v, off, 64);
    return v;
}
__device__ __forceinline__ void gload_lds16(const void* g, void* l) {
    __builtin_amdgcn_global_load_lds(
        (const __attribute__((address_space(1))) void*)(uintptr_t)g,
        (__attribute__((address_space(3))) void*)(uintptr_t)l,
        16, 0, 0);
}

// ---------- kernel 1: paired normalize -> bf16, + positive-pair dot ----------
__global__ __launch_bounds__(256) void knorm2(const float* __restrict__ feat,
                                              ushort_t* __restrict__ fbf,
                                              float* __restrict__ posdot) {
    int i = blockIdx.x;           // [0, B)
    int tid = threadIdx.x;
    const float4* ra = reinterpret_cast<const float4*>(feat + (size_t)i * D_DIM);
    const float4* rb = reinterpret_cast<const float4*>(feat + (size_t)(i + B_SZ) * D_DIM);
    float4 a0 = ra[tid * 2], a1 = ra[tid * 2 + 1];
    float4 b0 = rb[tid * 2], b1 = rb[tid * 2 + 1];
    float sa = a0.x*a0.x + a0.y*a0.y + a0.z*a0.z + a0.w*a0.w
             + a1.x*a1.x + a1.y*a1.y + a1.z*a1.z + a1.w*a1.w;
    float sb = b0.x*b0.x + b0.y*b0.y + b0.z*b0.z + b0.w*b0.w
             + b1.x*b1.x + b1.y*b1.y + b1.z*b1.z + b1.w*b1.w;
    float dp = a0.x*b0.x + a0.y*b0.y + a0.z*b0.z + a0.w*b0.w
             + a1.x*b1.x + a1.y*b1.y + a1.z*b1.z + a1.w*b1.w;
    sa = waveReduceSum(sa);
    sb = waveReduceSum(sb);
    dp = waveReduceSum(dp);
    __shared__ float wsum[3][4];
    if ((tid & 63) == 0) {
        int wv = tid >> 6;
        wsum[0][wv] = sa; wsum[1][wv] = sb; wsum[2][wv] = dp;
    }
    __syncthreads();
    float ta = wsum[0][0] + wsum[0][1] + wsum[0][2] + wsum[0][3];
    float tb = wsum[1][0] + wsum[1][1] + wsum[1][2] + wsum[1][3];
    float td = wsum[2][0] + wsum[2][1] + wsum[2][2] + wsum[2][3];
    float ia = 1.0f / fmaxf(sqrtf(ta), 1e-12f);
    float ib = 1.0f / fmaxf(sqrtf(tb), 1e-12f);
    if (tid == 0) posdot[i] = td * ia * ib;
    uint4 oa, ob;
    oa.x = (unsigned)f2bf(a0.x * ia) | ((unsigned)f2bf(a0.y * ia) << 16);
    oa.y = (unsigned)f2bf(a0.z * ia) | ((unsigned)f2bf(a0.w * ia) << 16);
    oa.z = (unsigned)f2bf(a1.x * ia) | ((unsigned)f2bf(a1.y * ia) << 16);
    oa.w = (unsigned)f2bf(a1.z * ia) | ((unsigned)f2bf(a1.w * ia) << 16);
    ob.x = (unsigned)f2bf(b0.x * ib) | ((unsigned)f2bf(b0.y * ib) << 16);
    ob.y = (unsigned)f2bf(b0.z * ib) | ((unsigned)f2bf(b0.w * ib) << 16);
    ob.z = (unsigned)f2bf(b1.x * ib) | ((unsigned)f2bf(b1.y * ib) << 16);
    ob.w = (unsigned)f2bf(b1.z * ib) | ((unsigned)f2bf(b1.w * ib) << 16);
    reinterpret_cast<uint4*>(fbf + (size_t)i * D_DIM)[tid] = oa;
    reinterpret_cast<uint4*>(fbf + (size_t)(i + B_SZ) * D_DIM)[tid] = ob;
}

// ---------- kernel 2: symmetric Gram, 256x256 jobs, 1024 thr / 16 waves,
//            BK=32 triple-buffer, counted vmcnt(2), fused exp-reductions + copy.
// Jobs: bid<496 -> off-diag (R<C); bid>=496 -> diag (R==C==bid-496).
__global__ __launch_bounds__(GRAM_THREADS, 4) void kgram(
        const ushort_t* __restrict__ fbf,
        const float* __restrict__ tau_buf, const int* __restrict__ index,
        float* __restrict__ E, float* __restrict__ F,
        const float4* __restrict__ sIn, const float4* __restrict__ uIn,
        const float4* __restrict__ tIn, float* __restrict__ out) {
    const int raw = (int)blockIdx.x;
    const int bid = (raw & 7) * (NJOB / 8) + (raw >> 3);   // chunked XCD swizzle (528 = 8*66)
    int R, C;
    if (bid < 496) {   // off-diagonal, C-major: C(C-1)/2 <= bid < C(C+1)/2
        C = (int)((1.0f + sqrtf(1.0f + 8.0f * (float)bid)) * 0.5f);
        while (C * (C - 1) / 2 > bid) --C;
        while ((C + 1) * C / 2 <= bid) ++C;
        R = bid - C * (C - 1) / 2;
    } else {
        C = bid - 496; R = C;
    }
    const int r0 = R * 256, c0 = C * 256;

    const int tid = threadIdx.x;
    const int lane = tid & 63;
    const int w = tid >> 6;            // wave 0..15
    const int wr = w >> 2;             // 0..3 (M)
    const int wc = w & 3;              // 0..3 (N)
    const int l15 = lane & 15, lhi = lane >> 4;

    __shared__ alignas(16) ushort_t As[3][256 * 32];   // 48 KB
    __shared__ alignas(16) ushort_t Bs[3][256 * 32];   // 48 KB

    f32x4 acc[4][4] = {};

    // staging: wave w stages 16 rows of A and 16 rows of B (1 gload each).
    // source-swizzle: global chunk = (l&3) ^ ((l>>3)&3); read-side XOR matches.
    const int srow = lane >> 2;
    const int schk = (lane & 3) ^ ((lane >> 3) & 3);
    const uint32_t gA = (uint32_t)(r0 + w * 16 + srow) * D_DIM + schk * 8;
    const uint32_t gB = (uint32_t)(c0 + w * 16 + srow) * D_DIM + schk * 8;
    const int lw = w * 16 * 32;        // element offset of this wave's 16-row slab

#define STAGE(buf, t)                                              \
    do {                                                           \
        uint32_t k_ = (uint32_t)(t) * 32u;                         \
        gload_lds16(fbf + gA + k_, &As[buf][lw]);                  \
        gload_lds16(fbf + gB + k_, &Bs[buf][lw]);                  \
    } while (0)

    // prologue: stage tiles 0,1; wait tile 0 (tile 1 stays in flight)
    STAGE(0, 0);
    STAGE(1, 1);
    asm volatile("s_waitcnt vmcnt(2)" ::: "memory");
    __builtin_amdgcn_sched_barrier(0);
    __builtin_amdgcn_s_barrier();

    const int rdch = (lhi ^ ((l15 >> 1) & 3)) * 8;   // swizzled read chunk (elements)
    int bufc = 0;
    for (int t = 0; t < NT; ++t) {
        if (t + 2 < NT) {
            int bw = (bufc >= 1) ? bufc - 1 : 2;     // (bufc+2)%3
            STAGE(bw, t + 2);
        }
        const ushort_t* __restrict__ A_l = &As[bufc][0];
        const ushort_t* __restrict__ B_l = &Bs[bufc][0];
        bf16x8 af[4], bfr[4];
#pragma unroll
        for (int m = 0; m < 4; ++m)
            af[m] = *reinterpret_cast<const bf16x8*>(&A_l[(wr * 64 + m * 16 + l15) * 32 + rdch]);
#pragma unroll
        for (int n = 0; n < 4; ++n)
            bfr[n] = *reinterpret_cast<const bf16x8*>(&B_l[(wc * 64 + n * 16 + l15) * 32 + rdch]);
        __builtin_amdgcn_s_setprio(1);
#pragma unroll
        for (int m = 0; m < 4; ++m)
#pragma unroll
            for (int n = 0; n < 4; ++n)
                acc[m][n] = __builtin_amdgcn_mfma_f32_16x16x32_bf16(af[m], bfr[n], acc[m][n], 0, 0, 0);
        __builtin_amdgcn_s_setprio(0);
        if (t < NT - 2) {
            asm volatile("s_waitcnt vmcnt(2)" ::: "memory");   // tile t+1 landed; t+2 flies
        } else if (t == NT - 2) {
            asm volatile("s_waitcnt vmcnt(0)" ::: "memory");
        }
        __builtin_amdgcn_sched_barrier(0);
        if (t < NT - 1) __builtin_amdgcn_s_barrier();
        bufc = (bufc == 2) ? 0 : bufc + 1;
    }
#undef STAGE

    // ---- epilogue: per element col>row -> direct (row tau) + transposed (col tau) ----
#pragma unroll
    for (int m = 0; m < 4; ++m) {
#pragma unroll
        for (int r = 0; r < 4; ++r) {
            int row_g = r0 + wr * 64 + m * 16 + lhi * 4 + r;
            float it = 1.0f / tau_buf[index[row_g & (B_SZ - 1)]];
            float e = 0.f, f = 0.f;
#pragma unroll
            for (int n = 0; n < 4; ++n) {
                int col_g = c0 + wc * 64 + n * 16 + l15;
                float v = acc[m][n][r];
                if (col_g > row_g && (((row_g ^ col_g) & (B_SZ - 1)) != 0)) {
                    float ex = __expf(v * it);
                    e += ex;
                    f += ex * v;
                }
            }
#pragma unroll
            for (int off = 1; off < 16; off <<= 1) {
                e += __shfl_xor(e, off, 64);
                f += __shfl_xor(f, off, 64);
            }
            if (l15 == 0) {
                atomicAdd(&E[row_g], e);
                atomicAdd(&F[row_g], f);
            }
        }
    }
#pragma unroll
    for (int n = 0; n < 4; ++n) {
        int colT = c0 + wc * 64 + n * 16 + l15;
        float it = 1.0f / tau_buf[index[colT & (B_SZ - 1)]];
        float e = 0.f, f = 0.f;
#pragma unroll
        for (int m = 0; m < 4; ++m) {
#pragma unroll
            for (int r = 0; r < 4; ++r) {
                int row_g = r0 + wr * 64 + m * 16 + lhi * 4 + r;
                float v = acc[m][n][r];
                if (colT > row_g && (((row_g ^ colT) & (B_SZ - 1)) != 0)) {
                    float ex = __expf(v * it);
                    e += ex;
                    f += ex * v;
                }
            }
        }
        e += __shfl_xor(e, 16, 64);
        f += __shfl_xor(f, 16, 64);
        e += __shfl_xor(e, 32, 64);
        f += __shfl_xor(f, 32, 64);
        if (lhi == 0) {
            atomicAdd(&E[colT], e);
            atomicAdd(&F[colT], f);
        }
    }

    // ---- fused bulk copy s/u/tau -> out ----
    {
        typedef float4 __attribute__((aligned(4))) float4u;
        size_t i = (size_t)raw * GRAM_THREADS + tid;
        const size_t stride = (size_t)NJOB * GRAM_THREADS;
        const size_t n4 = N_TOT / 4;
        for (; i < n4; i += stride) {
            *reinterpret_cast<float4u*>(out + 1 + 4 * i) = sIn[i];
            *reinterpret_cast<float4u*>(out + 1 + (size_t)N_TOT + 4 * i) = uIn[i];
            *reinterpret_cast<float4u*>(out + 1 + 2 * (size_t)N_TOT + 4 * i) = tIn[i];
        }
    }
}

// ---------- kernel 3: finalize per positive pair ----------
__global__ __launch_bounds__(64) void kfin(const float* __restrict__ E,
                                           const float* __restrict__ F,
                                           const float* __restrict__ posdot,
                                           const float* __restrict__ s,
                                           const float* __restrict__ tau_buf,
                                           const float* __restrict__ u_buf,
                                           const int* __restrict__ index,
                                           const int* __restrict__ epoch_p,
                                           float* __restrict__ out) {
    int i = blockIdx.x;     // [0, B)
    int lane = threadIdx.x; // [0, 64)
    int idx = index[i];
    bool dup = false;
    for (int j = i + 1 + lane; j < B_SZ; j += 64)
        if (index[j] == idx) dup = true;
    unsigned long long ball = __ballot(dup);

    if (lane == 0) {
        float e1 = E[i], f1 = F[i];
        float e2 = E[i + B_SZ], f2 = F[i + B_SZ];
        const float num_neg = 2.0f * B_SZ - 2.0f;
        float g1 = e1 / num_neg, g2 = e2 / num_neg;
        float s_old = s[idx];
        float tau_i = tau_buf[idx];
        float u_old = u_buf[idx];
        int ep = *epoch_p;
        float s1, s2;
        if (ep == 0) { s1 = g1; s2 = g2; }
        else { s1 = 0.2f * s_old + 0.8f * g1; s2 = 0.2f * s_old + 0.8f * g2; }
        float pos = posdot[i];
        float l1 = f1 / (s1 * num_neg) - pos;
        float l2 = f2 / (s2 * num_neg) - pos;
        atomicAdd(out, (l1 + l2) * (1.0f / B_SZ));
        float gt1 = logf(s1) + RHO - f1 / (tau_i * s1 * num_neg);
        float gt2 = logf(s2) + RHO - f2 / (tau_i * s2 * num_neg);
        float gt = 0.5f * (gt1 + gt2);
        gt = fminf(fmaxf(gt, -3.0f), 3.0f);
        float u_new = 0.1f * u_old + 0.9f * gt;
        float tau_new = fminf(fmaxf(tau_i - 0.001f * u_new, 0.05f), 1.0f);
        if (ball == 0ULL) {  // winner (numpy last-wins)
            out[1 + (size_t)idx] = 0.5f * (s1 + s2);
            out[1 + (size_t)N_TOT + idx] = u_new;
            out[1 + 2 * (size_t)N_TOT + idx] = tau_new;
        }
    }
}

extern "C" void kernel_launch(void* const* d_in, const int* in_sizes, int n_in,
                              void* d_out, int out_size, void* d_ws, size_t ws_size,
                              hipStream_t stream) {
    const float* features = (const float*)d_in[0];
    const float* s        = (const float*)d_in[1];
    const float* tau_buf  = (const float*)d_in[2];
    const float* u_buf    = (const float*)d_in[3];
    const int*   index    = (const int*)d_in[4];
    const int*   epoch    = (const int*)d_in[5];
    float* out = (float*)d_out;
    char* ws = (char*)d_ws;

    // workspace layout
    ushort_t* fbf    = (ushort_t*)(ws);                  // 33,554,432 B
    float*    E      = (float*)(ws + 33554432);          // 32 KB
    float*    F      = (float*)(ws + 33587200);          // 32 KB
    float*    posdot = (float*)(ws + 33619968);          // 16 KB

    hipMemsetAsync(d_out, 0, sizeof(float), stream);           // loss accumulator
    hipMemsetAsync(E, 0, 2 * TWO_B * sizeof(float), stream);   // E and F (contiguous)

    knorm2<<<B_SZ, 256, 0, stream>>>(features, fbf, posdot);
    kgram<<<NJOB, GRAM_THREADS, 0, stream>>>(fbf, tau_buf, index, E, F,
                                             (const float4*)s, (const float4*)u_buf,
                                             (const float4*)tau_buf, out);
    kfin<<<B_SZ, 64, 0, stream>>>(E, F, posdot, s, tau_buf, u_buf, index, epoch, out);
}